// Round 1
// baseline (1450.375 us; speedup 1.0000x reference)
//
#include <hip/hip_runtime.h>
#include <math.h>

#define Bq 64
#define Hq 256
#define Lq 1024
#define Nq 128
#define Gq 8
#define HSq 256
#define BHL (Bq*Hq*Lq)

// ---------------- GroupNorm stats: one block per (b,g) --------------------
__global__ __launch_bounds__(256) void k_stats(const float* __restrict__ x,
                                               float* __restrict__ stats) {
    int bg = blockIdx.x;                       // (b*G + g)
    const float* xp = x + (size_t)bg * (32 * Lq);   // group region is contiguous
    float s1 = 0.f, s2 = 0.f;
    for (int i = threadIdx.x; i < 32 * Lq / 4; i += 256) {
        float4 v = ((const float4*)xp)[i];
        s1 += v.x + v.y + v.z + v.w;
        s2 += v.x*v.x + v.y*v.y + v.z*v.z + v.w*v.w;
    }
    __shared__ float r1[256], r2[256];
    r1[threadIdx.x] = s1; r2[threadIdx.x] = s2;
    __syncthreads();
    for (int s = 128; s > 0; s >>= 1) {
        if (threadIdx.x < s) { r1[threadIdx.x] += r1[threadIdx.x+s];
                               r2[threadIdx.x] += r2[threadIdx.x+s]; }
        __syncthreads();
    }
    if (threadIdx.x == 0) {
        const float inv = 1.f / (32.f * Lq);
        float mu  = r1[0] * inv;
        float var = r2[0] * inv - mu * mu;
        stats[bg*2]   = mu;
        stats[bg*2+1] = rsqrtf(var + 1e-5f);
    }
}

// ---------------- diffusion projection d[b,o] -----------------------------
__global__ __launch_bounds__(256) void k_dproj(const float* __restrict__ emb,
                                               const float* __restrict__ dw,
                                               const float* __restrict__ db,
                                               float* __restrict__ d) {
    int i = blockIdx.x * 256 + threadIdx.x;    // [0, B*H)
    int b = i >> 8, o = i & 255;
    const float* e = emb + b * 256;
    const float* w = dw + o * 256;
    float acc = 0.f;
    for (int k = 0; k < 256; k += 4) {
        float4 ev = *(const float4*)(e + k);
        float4 wv = *(const float4*)(w + k);
        acc += ev.x*wv.x + ev.y*wv.y + ev.z*wv.z + ev.w*wv.w;
    }
    d[i] = acc + db[o];
}

// ---------------- u = gn(x)*w + b + d ------------------------------------
__global__ __launch_bounds__(256) void k_u(const float* __restrict__ x,
                                           const float* __restrict__ stats,
                                           const float* __restrict__ gnw,
                                           const float* __restrict__ gnb,
                                           const float* __restrict__ d,
                                           float* __restrict__ u) {
    int n4 = BHL / 4;
    for (int i = blockIdx.x * blockDim.x + threadIdx.x; i < n4;
         i += gridDim.x * blockDim.x) {
        int flat = i * 4;
        int bc = flat >> 10;                   // b*H + c   (L = 1024)
        int b = bc >> 8, c = bc & 255;
        int g = c >> 5;
        float mu = stats[(b*Gq+g)*2], rs = stats[(b*Gq+g)*2+1];
        float sc = rs * gnw[c];
        float sh = gnb[c] + d[bc] - mu * sc;
        float4 v = ((const float4*)x)[i];
        float4 o;
        o.x = v.x*sc + sh; o.y = v.y*sc + sh;
        o.z = v.z*sc + sh; o.w = v.w*sc + sh;
        ((float4*)u)[i] = o;
    }
}

// ---------------- S4D kernel K[h,l] ---------------------------------------
__global__ __launch_bounds__(256) void k_kern(const float* __restrict__ log_dt,
                                              const float* __restrict__ Are,
                                              const float* __restrict__ Aim,
                                              const float* __restrict__ Cre,
                                              const float* __restrict__ Cim,
                                              float* __restrict__ Kg) {
    int h = blockIdx.x;
    __shared__ float ctr[Nq], cti[Nq], kan[Nq], kbn[Nq];
    if (threadIdx.x < Nq) {
        int n = threadIdx.x;
        float dt = expf(log_dt[h]);
        float ar = Are[h*Nq+n], ai = Aim[h*Nq+n];
        float a = dt * ar, bb = dt * ai;
        float e = expf(a);
        float er = e * cosf(bb) - 1.f;         // exp(dtA) - 1
        float ei = e * sinf(bb);
        float den = ar*ar + ai*ai;
        float dr = (er*ar + ei*ai) / den;      // (exp(dtA)-1)/A
        float di = (ei*ar - er*ai) / den;
        float cr = Cre[h*Nq+n], ci = Cim[h*Nq+n];
        ctr[n] = cr*dr - ci*di;
        cti[n] = cr*di + ci*dr;
        kan[n] = a; kbn[n] = bb;
    }
    __syncthreads();
    for (int rep = 0; rep < 4; rep++) {
        int l = rep * 256 + threadIdx.x;
        float fl = (float)l;
        float acc = 0.f;
        for (int n = 0; n < Nq; n++) {
            float E = expf(kan[n] * fl);
            float s, c;
            sincosf(kbn[n] * fl, &s, &c);
            acc += E * (ctr[n]*c - cti[n]*s);
        }
        Kg[h*Lq + l] = 2.f * acc;
    }
}

// ---------------- causal conv + D*u + gelu  -> gy -------------------------
// block = (h, 128-wide l tile) covering all 64 batches
// thread tile: 4 batches x 8 l ; k-loop over t in chunks of 32 (LDS staged)
__global__ __launch_bounds__(256, 3) void k_conv(const float* __restrict__ u,
                                                 const float* __restrict__ Kg,
                                                 const float* __restrict__ Dp,
                                                 float* __restrict__ gy) {
    int h  = blockIdx.x >> 3;
    int l0 = (blockIdx.x & 7) << 7;
    __shared__ float kbuf[1152];               // [128 zero pad][K 0..l0+127]
    __shared__ float ut[64][36];               // 64 batches x 32 t (+pad)
    int tid = threadIdx.x;
    int nk = l0 + 128;
    for (int i = tid; i < 128 + nk; i += 256)
        kbuf[i] = (i < 128) ? 0.f : Kg[h*Lq + (i - 128)];

    float acc[4][8];
#pragma unroll
    for (int a = 0; a < 4; a++)
#pragma unroll
        for (int b = 0; b < 8; b++) acc[a][b] = 0.f;

    int tcol = tid & 15, trow = tid >> 4;
    int L0c = l0 + tcol * 8;

    for (int t0 = 0; t0 < nk; t0 += 32) {
        __syncthreads();
#pragma unroll
        for (int r = 0; r < 2; r++) {
            int idx = r * 256 + tid;
            int b = idx >> 3, tq = (idx & 7) << 2;
            float4 v = *(const float4*)(u + ((size_t)(b*Hq + h))*Lq + t0 + tq);
            *(float4*)&ut[b][tq] = v;
        }
        __syncthreads();
#pragma unroll
        for (int ts = 0; ts < 32; ts += 8) {
            float W[16];
            int kw = 128 + L0c - t0 - ts - 8;
#pragma unroll
            for (int i = 0; i < 4; i++)
                *(float4*)&W[i*4] = *(const float4*)&kbuf[kw + i*4];
#pragma unroll
            for (int bb = 0; bb < 4; bb++) {
                float uf[8];
                *(float4*)&uf[0] = *(const float4*)&ut[trow*4+bb][ts];
                *(float4*)&uf[4] = *(const float4*)&ut[trow*4+bb][ts+4];
#pragma unroll
                for (int tt = 0; tt < 8; tt++)
#pragma unroll
                    for (int ll = 0; ll < 8; ll++)
                        acc[bb][ll] += uf[tt] * W[8 + ll - tt];
            }
        }
    }
    float Dh = Dp[h];
#pragma unroll
    for (int bb = 0; bb < 4; bb++) {
        int b = trow*4 + bb;
        const float* up = u  + ((size_t)(b*Hq + h))*Lq + L0c;
        float*       gp = gy + ((size_t)(b*Hq + h))*Lq + L0c;
        float uv[8];
        *(float4*)&uv[0] = *(const float4*)up;
        *(float4*)&uv[4] = *(const float4*)(up + 4);
        float o[8];
#pragma unroll
        for (int ll = 0; ll < 8; ll++) {
            float y = acc[bb][ll] + Dh * uv[ll];
            float t = 0.7978845608028654f * (y + 0.044715f*y*y*y);
            o[ll] = 0.5f * y * (1.f + tanhf(t));      // jax gelu approximate=True
        }
        *(float4*)gp       = *(float4*)&o[0];
        *(float4*)(gp + 4) = *(float4*)&o[4];
    }
}

// ------- fused: v=out_w@gy+ob ; GLU ; h2=glu+u ; res/skip projections -----
// block = (b, 32-wide l tile); 512 rows; thread tile 8 rows x 8 cols
__global__ __launch_bounds__(256, 3) void k_proj(const float* __restrict__ gy,
                                                 const float* __restrict__ u,
                                                 const float* __restrict__ x,
                                                 const float* __restrict__ ow,
                                                 const float* __restrict__ ob,
                                                 const float* __restrict__ rw,
                                                 const float* __restrict__ rb,
                                                 const float* __restrict__ sw,
                                                 const float* __restrict__ sb,
                                                 float* __restrict__ out) {
    int b  = blockIdx.x >> 5;
    int l0 = (blockIdx.x & 31) << 5;
    __shared__ float act[256 * 32];            // 32 KB activation tile
    __shared__ float wt[512 * 8];              // 16 KB weight k-chunk
    int tid = threadIdx.x;
    int cg = tid & 3;                          // 4 col groups x 8 cols
    int rg = tid >> 2;                         // 64 row groups; rows rg + 64*i

    // stage act = gy tile [256 ch][32 l]
    for (int i = tid; i < 2048; i += 256) {
        int ch = i >> 3, part = i & 7;
        float4 v = *(const float4*)(gy + ((size_t)(b*Hq + ch))*Lq + l0 + part*4);
        *(float4*)&act[ch*32 + part*4] = v;
    }

    float acc[8][8];
    for (int pass = 0; pass < 2; pass++) {
#pragma unroll
        for (int i = 0; i < 8; i++)
#pragma unroll
            for (int j = 0; j < 8; j++) acc[i][j] = 0.f;

        for (int k0 = 0; k0 < 256; k0 += 8) {
            __syncthreads();
            for (int i = tid; i < 1024; i += 256) {
                int r = i >> 1, half = i & 1;
                const float* wsrc;
                if (pass == 0) wsrc = ow + r*256;
                else wsrc = (r < 256) ? (rw + r*256) : (sw + (r - 256)*256);
                float4 v = *(const float4*)(wsrc + k0 + half*4);
                *(float4*)&wt[r*8 + half*4] = v;
            }
            __syncthreads();
#pragma unroll
            for (int sub = 0; sub < 2; sub++) {
                float bf[4][8];
#pragma unroll
                for (int kk = 0; kk < 4; kk++) {
                    int k = k0 + sub*4 + kk;
                    *(float4*)&bf[kk][0] = *(const float4*)&act[k*32 + cg*8];
                    *(float4*)&bf[kk][4] = *(const float4*)&act[k*32 + cg*8 + 4];
                }
#pragma unroll
                for (int i = 0; i < 8; i++) {
                    float wf[4];
                    *(float4*)&wf[0] = *(const float4*)&wt[(rg + 64*i)*8 + sub*4];
#pragma unroll
                    for (int kk = 0; kk < 4; kk++)
#pragma unroll
                        for (int cc = 0; cc < 8; cc++)
                            acc[i][cc] += wf[kk] * bf[kk][cc];
                }
            }
        }

        if (pass == 0) {
            __syncthreads();   // all act (gy) reads complete
            // GLU + inner residual, write h2 into act tile
#pragma unroll
            for (int i = 0; i < 4; i++) {
                int r = rg + 64*i;             // [0,256); pair row = r+256 (i+4)
                float uv[8];
                const float* up = u + ((size_t)(b*Hq + r))*Lq + l0 + cg*8;
                *(float4*)&uv[0] = *(const float4*)up;
                *(float4*)&uv[4] = *(const float4*)(up + 4);
                float b1 = ob[r], b2 = ob[r + 256];
                float h2[8];
#pragma unroll
                for (int cc = 0; cc < 8; cc++) {
                    float v1 = acc[i][cc]   + b1;
                    float v2 = acc[i+4][cc] + b2;
                    float sg = 1.f / (1.f + expf(-v2));
                    h2[cc] = v1 * sg + uv[cc];
                }
                *(float4*)&act[r*32 + cg*8]     = *(float4*)&h2[0];
                *(float4*)&act[r*32 + cg*8 + 4] = *(float4*)&h2[4];
            }
        } else {
            // epilogue B: res rows (i<4), skip rows (i>=4)
#pragma unroll
            for (int i = 0; i < 4; i++) {
                int r = rg + 64*i;
                const float* xp = x + ((size_t)(b*Hq + r))*Lq + l0 + cg*8;
                float xv[8];
                *(float4*)&xv[0] = *(const float4*)xp;
                *(float4*)&xv[4] = *(const float4*)(xp + 4);
                float rbv = rb[r];
                float o1[8];
#pragma unroll
                for (int cc = 0; cc < 8; cc++)
                    o1[cc] = (acc[i][cc] + rbv + xv[cc]) * 0.70710678118654752f;
                float* op = out + ((size_t)(b*Hq + r))*Lq + l0 + cg*8;
                *(float4*)op       = *(float4*)&o1[0];
                *(float4*)(op + 4) = *(float4*)&o1[4];

                float sbv = sb[r];
                float o2[8];
#pragma unroll
                for (int cc = 0; cc < 8; cc++)
                    o2[cc] = acc[i+4][cc] + sbv;
                float* sp = out + (size_t)BHL + ((size_t)(b*HSq + r))*Lq + l0 + cg*8;
                *(float4*)sp       = *(float4*)&o2[0];
                *(float4*)(sp + 4) = *(float4*)&o2[4];
            }
        }
    }
}

extern "C" void kernel_launch(void* const* d_in, const int* in_sizes, int n_in,
                              void* d_out, int out_size, void* d_ws, size_t ws_size,
                              hipStream_t stream) {
    const float* x      = (const float*)d_in[0];
    const float* emb    = (const float*)d_in[1];
    const float* gnw    = (const float*)d_in[2];
    const float* gnb    = (const float*)d_in[3];
    const float* dpw    = (const float*)d_in[4];
    const float* dpb    = (const float*)d_in[5];
    const float* log_dt = (const float*)d_in[6];
    const float* Are    = (const float*)d_in[7];
    const float* Aim    = (const float*)d_in[8];
    const float* Cre    = (const float*)d_in[9];
    const float* Cim    = (const float*)d_in[10];
    const float* Dp     = (const float*)d_in[11];
    const float* ow     = (const float*)d_in[12];
    const float* ob     = (const float*)d_in[13];
    const float* rw     = (const float*)d_in[14];
    const float* rb     = (const float*)d_in[15];
    const float* sw     = (const float*)d_in[16];
    const float* sb     = (const float*)d_in[17];
    float* out = (float*)d_out;

    float* u     = (float*)d_ws;                       // [B,H,L]
    float* gy    = u  + (size_t)BHL;                   // [B,H,L]
    float* Kg    = gy + (size_t)BHL;                   // [H,L]
    float* d     = Kg + (size_t)Hq*Lq;                 // [B,H]
    float* stats = d  + (size_t)Bq*Hq;                 // [B*G][2]

    k_stats<<<Bq*Gq, 256, 0, stream>>>(x, stats);
    k_dproj<<<Bq*Hq/256, 256, 0, stream>>>(emb, dpw, dpb, d);
    k_u<<<2048, 256, 0, stream>>>(x, stats, gnw, gnb, d, u);
    k_kern<<<Hq, 256, 0, stream>>>(log_dt, Are, Aim, Cre, Cim, Kg);
    k_conv<<<Hq*8, 256, 0, stream>>>(u, Kg, Dp, gy);
    k_proj<<<Bq*32, 256, 0, stream>>>(gy, u, x, ow, ob, rw, rb, sw, sb, out);
}

// Round 2
// 621.260 us; speedup vs baseline: 2.3346x; 2.3346x over previous
//
#include <hip/hip_runtime.h>
#include <math.h>

#define Bq 64
#define Hq 256
#define Lq 1024
#define Nq 128
#define Gq 8
#define HSq 256
#define BHL (Bq*Hq*Lq)

typedef __bf16 bf16_t;
typedef __bf16 bf16x8 __attribute__((ext_vector_type(8)));
typedef float f32x4 __attribute__((ext_vector_type(4)));

union U2 { uint2 u; bf16_t e[4]; };
union F4 { float4 v; float e[4]; };

// ---------------- GroupNorm stats: one block per (b,g) --------------------
__global__ __launch_bounds__(256) void k_stats(const float* __restrict__ x,
                                               float* __restrict__ stats) {
    int bg = blockIdx.x;
    const float* xp = x + (size_t)bg * (32 * Lq);
    float s1 = 0.f, s2 = 0.f;
    for (int i = threadIdx.x; i < 32 * Lq / 4; i += 256) {
        float4 v = ((const float4*)xp)[i];
        s1 += v.x + v.y + v.z + v.w;
        s2 += v.x*v.x + v.y*v.y + v.z*v.z + v.w*v.w;
    }
    __shared__ float r1[256], r2[256];
    r1[threadIdx.x] = s1; r2[threadIdx.x] = s2;
    __syncthreads();
    for (int s = 128; s > 0; s >>= 1) {
        if (threadIdx.x < s) { r1[threadIdx.x] += r1[threadIdx.x+s];
                               r2[threadIdx.x] += r2[threadIdx.x+s]; }
        __syncthreads();
    }
    if (threadIdx.x == 0) {
        const float inv = 1.f / (32.f * Lq);
        float mu  = r1[0] * inv;
        float var = r2[0] * inv - mu * mu;
        stats[bg*2]   = mu;
        stats[bg*2+1] = rsqrtf(var + 1e-5f);
    }
}

// ---------------- diffusion projection d[b,o] -----------------------------
__global__ __launch_bounds__(256) void k_dproj(const float* __restrict__ emb,
                                               const float* __restrict__ dw,
                                               const float* __restrict__ db,
                                               float* __restrict__ d) {
    int i = blockIdx.x * 256 + threadIdx.x;
    int b = i >> 8, o = i & 255;
    const float* e = emb + b * 256;
    const float* w = dw + o * 256;
    float acc = 0.f;
    for (int k = 0; k < 256; k += 4) {
        float4 ev = *(const float4*)(e + k);
        float4 wv = *(const float4*)(w + k);
        acc += ev.x*wv.x + ev.y*wv.y + ev.z*wv.z + ev.w*wv.w;
    }
    d[i] = acc + db[o];
}

// ---------------- u = gn(x)*w + b + d  (bf16 out) -------------------------
__global__ __launch_bounds__(256) void k_u(const float* __restrict__ x,
                                           const float* __restrict__ stats,
                                           const float* __restrict__ gnw,
                                           const float* __restrict__ gnb,
                                           const float* __restrict__ d,
                                           bf16_t* __restrict__ ub) {
    int n4 = BHL / 4;
    for (int i = blockIdx.x * blockDim.x + threadIdx.x; i < n4;
         i += gridDim.x * blockDim.x) {
        int flat = i * 4;
        int bc = flat >> 10;
        int b = bc >> 8, c = bc & 255;
        int g = c >> 5;
        float mu = stats[(b*Gq+g)*2], rs = stats[(b*Gq+g)*2+1];
        float sc = rs * gnw[c];
        float sh = gnb[c] + d[bc] - mu * sc;
        float4 v = ((const float4*)x)[i];
        U2 o;
        o.e[0] = (bf16_t)(v.x*sc + sh);
        o.e[1] = (bf16_t)(v.y*sc + sh);
        o.e[2] = (bf16_t)(v.z*sc + sh);
        o.e[3] = (bf16_t)(v.w*sc + sh);
        *(uint2*)&ub[(size_t)flat] = o.u;
    }
}

// ---------------- transpose [B][256][1024] -> [B][1024][256] (bf16) -------
__global__ __launch_bounds__(256) void k_tr(const bf16_t* __restrict__ src,
                                            bf16_t* __restrict__ dst) {
    int b  = blockIdx.x >> 6;
    int r0 = ((blockIdx.x >> 4) & 3) << 6;
    int c0 = (blockIdx.x & 15) << 6;
    __shared__ __align__(16) bf16_t t[64][72];   // 144B rows (9x16B)
    int tid = threadIdx.x;
    int r = tid >> 2, cs = (tid & 3) * 16;
    const bf16_t* sp = src + ((size_t)b*256 + r0 + r)*1024 + c0 + cs;
    union { uint4 u; bf16_t e[8]; } v0, v1;
    v0.u = *(const uint4*)sp;
    v1.u = *(const uint4*)(sp + 8);
#pragma unroll
    for (int j = 0; j < 8; j++) { t[cs + j][r] = v0.e[j]; t[cs + 8 + j][r] = v1.e[j]; }
    __syncthreads();
    bf16_t* dp = dst + ((size_t)b*1024 + c0 + r)*256 + r0 + (tid & 3)*16;
    *(uint4*)dp       = *(const uint4*)&t[r][(tid & 3)*16];
    *(uint4*)(dp + 8) = *(const uint4*)&t[r][(tid & 3)*16 + 8];
}

// ---------------- weights fp32 -> bf16 ------------------------------------
__global__ __launch_bounds__(256) void k_wcvt(const float* __restrict__ ow,
                                              const float* __restrict__ rw,
                                              const float* __restrict__ sw,
                                              bf16_t* __restrict__ owb,
                                              bf16_t* __restrict__ rsb) {
    int i = blockIdx.x * 256 + threadIdx.x;      // [0, 131072)
    owb[i] = (bf16_t)ow[i];
    rsb[i] = (bf16_t)((i < 65536) ? rw[i] : sw[i - 65536]);
}

// ---------------- S4D kernel -> reversed padded bf16 Krev -----------------
// Krev[h][j] = (256 <= j <= 1279) ? K[h][1279 - j] : 0 ;  row size 1536
__global__ __launch_bounds__(256) void k_kern(const float* __restrict__ log_dt,
                                              const float* __restrict__ Are,
                                              const float* __restrict__ Aim,
                                              const float* __restrict__ Cre,
                                              const float* __restrict__ Cim,
                                              bf16_t* __restrict__ Krev) {
    int h = blockIdx.x;
    __shared__ float ctr[Nq], cti[Nq], kan[Nq], kbn[Nq];
    int tid = threadIdx.x;
    if (tid < Nq) {
        int n = tid;
        float dt = expf(log_dt[h]);
        float ar = Are[h*Nq+n], ai = Aim[h*Nq+n];
        float a = dt * ar, bb = dt * ai;
        float e = expf(a);
        float er = e * cosf(bb) - 1.f;
        float ei = e * sinf(bb);
        float den = ar*ar + ai*ai;
        float dr = (er*ar + ei*ai) / den;
        float di = (ei*ar - er*ai) / den;
        float cr = Cre[h*Nq+n], ci = Cim[h*Nq+n];
        ctr[n] = cr*dr - ci*di;
        cti[n] = cr*di + ci*dr;
        kan[n] = a; kbn[n] = bb;
    }
    bf16_t* Kh = Krev + (size_t)h * 1536;
    Kh[tid]        = (bf16_t)0.f;
    Kh[1280 + tid] = (bf16_t)0.f;
    __syncthreads();
    for (int rep = 0; rep < 4; rep++) {
        int l = rep * 256 + tid;
        float fl = (float)l;
        float acc = 0.f;
        for (int n = 0; n < Nq; n++) {
            float E = expf(kan[n] * fl);
            float s, c;
            sincosf(kbn[n] * fl, &s, &c);
            acc += E * (ctr[n]*c - cti[n]*s);
        }
        Kh[1279 - l] = (bf16_t)(2.f * acc);
    }
}

// ---------------- causal conv (Toeplitz MFMA) + D*u + gelu -> gy bf16 -----
// block: (h, 256-l tile). C tile [m=l:256][n=b:64]; K-dim t in chunks of 32.
__global__ __launch_bounds__(256) void k_conv(const bf16_t* __restrict__ ub,
                                              const bf16_t* __restrict__ Krev,
                                              const float* __restrict__ Dp,
                                              bf16_t* __restrict__ gy) {
    int h  = blockIdx.x >> 2;
    int l0 = (blockIdx.x & 3) << 8;
    __shared__ __align__(16) bf16_t krv[288];
    __shared__ __align__(16) bf16_t ut[64*32];
    int tid = threadIdx.x, lane = tid & 63, wv = tid >> 6;
    int q = lane >> 4, ln = lane & 15;

    f32x4 acc[4][4];
#pragma unroll
    for (int a = 0; a < 4; a++)
#pragma unroll
        for (int c = 0; c < 4; c++) acc[a][c] = (f32x4){0.f,0.f,0.f,0.f};

    const bf16_t* Kh = Krev + (size_t)h * 1536;
    int nt = l0 + 256;
    for (int t0 = 0; t0 < nt; t0 += 32) {
        __syncthreads();
        if (tid < 36)
            *(uint4*)&krv[tid*8] = *(const uint4*)&Kh[(1024 - l0 + t0) + tid*8];
        {
            int bb = tid >> 2, seg = tid & 3;
            *(uint4*)&ut[bb*32 + seg*8] =
                *(const uint4*)&ub[((size_t)bb*Hq + h)*Lq + t0 + seg*8];
        }
        __syncthreads();
        bf16x8 bfr[4];
#pragma unroll
        for (int nf = 0; nf < 4; nf++)
            bfr[nf] = *(const bf16x8*)&ut[(nf*16 + ln)*32 + q*8];
#pragma unroll
        for (int mf = 0; mf < 4; mf++) {
            int m = wv*64 + mf*16 + ln;
            union { bf16x8 v; bf16_t e[8]; } af;
            int sb0 = 255 - m + q*8;
#pragma unroll
            for (int j = 0; j < 8; j++) af.e[j] = krv[sb0 + j];
#pragma unroll
            for (int nf = 0; nf < 4; nf++)
                acc[mf][nf] = __builtin_amdgcn_mfma_f32_16x16x32_bf16(
                    af.v, bfr[nf], acc[mf][nf], 0, 0, 0);
        }
    }
    float Dh = Dp[h];
#pragma unroll
    for (int mf = 0; mf < 4; mf++) {
        int l = l0 + wv*64 + mf*16 + q*4;
#pragma unroll
        for (int nf = 0; nf < 4; nf++) {
            int bb = nf*16 + ln;
            size_t off = ((size_t)bb*Hq + h)*Lq + l;
            U2 uv; uv.u = *(const uint2*)&ub[off];
            U2 ov;
#pragma unroll
            for (int rr = 0; rr < 4; rr++) {
                float y = acc[mf][nf][rr] + Dh * (float)uv.e[rr];
                float t = 0.7978845608028654f * (y + 0.044715f*y*y*y);
                ov.e[rr] = (bf16_t)(0.5f * y * (1.f + tanhf(t)));
            }
            *(uint2*)&gy[off] = ov.u;
        }
    }
}

// ------- projA: v = ow@gy (MFMA) ; GLU ; h2 = glu + u -> h2T bf16 ---------
// m = o rows {o0..o0+63} U {o0+256..o0+319}; n = l (128); K = 256.
__global__ __launch_bounds__(256) void k_projA(const bf16_t* __restrict__ gyT,
                                               const bf16_t* __restrict__ owb,
                                               const float* __restrict__ ob,
                                               const bf16_t* __restrict__ ubT,
                                               bf16_t* __restrict__ h2T) {
    int bid = blockIdx.x;
    int og = bid >> 9;
    int b  = (bid >> 3) & 63;
    int l0 = (bid & 7) << 7;
    __shared__ __align__(16) bf16_t at[128*32];
    __shared__ __align__(16) bf16_t bt[128*32];
    int tid = threadIdx.x, lane = tid & 63, wv = tid >> 6;
    int q = lane >> 4, ln = lane & 15;
    int r = tid >> 2, seg = tid & 3;

    f32x4 acc[8][2];
#pragma unroll
    for (int i = 0; i < 8; i++) { acc[i][0] = (f32x4){0.f,0.f,0.f,0.f};
                                  acc[i][1] = (f32x4){0.f,0.f,0.f,0.f}; }

    for (int k0 = 0; k0 < 256; k0 += 32) {
        __syncthreads();
        *(uint4*)&at[r*32 + seg*8] =
            *(const uint4*)&owb[(og*64 + r)*256 + k0 + seg*8];
        *(uint4*)&at[(r+64)*32 + seg*8] =
            *(const uint4*)&owb[(256 + og*64 + r)*256 + k0 + seg*8];
        *(uint4*)&bt[r*32 + seg*8] =
            *(const uint4*)&gyT[((size_t)b*Lq + l0 + r)*256 + k0 + seg*8];
        *(uint4*)&bt[(r+64)*32 + seg*8] =
            *(const uint4*)&gyT[((size_t)b*Lq + l0 + 64 + r)*256 + k0 + seg*8];
        __syncthreads();
        bf16x8 bfr[2];
        bfr[0] = *(const bf16x8*)&bt[(wv*32 + ln)*32 + q*8];
        bfr[1] = *(const bf16x8*)&bt[(wv*32 + 16 + ln)*32 + q*8];
#pragma unroll
        for (int mf = 0; mf < 8; mf++) {
            bf16x8 af = *(const bf16x8*)&at[(mf*16 + ln)*32 + q*8];
            acc[mf][0] = __builtin_amdgcn_mfma_f32_16x16x32_bf16(af, bfr[0], acc[mf][0], 0,0,0);
            acc[mf][1] = __builtin_amdgcn_mfma_f32_16x16x32_bf16(af, bfr[1], acc[mf][1], 0,0,0);
        }
    }
#pragma unroll
    for (int nf = 0; nf < 2; nf++) {
        int l = l0 + wv*32 + nf*16 + ln;
        size_t base = ((size_t)b*Lq + l)*256;
#pragma unroll
        for (int mf = 0; mf < 4; mf++) {
            int o = og*64 + mf*16 + q*4;
            F4 b1, b2;
            b1.v = *(const float4*)&ob[o];
            b2.v = *(const float4*)&ob[o + 256];
            U2 uv; uv.u = *(const uint2*)&ubT[base + o];
            U2 hv;
#pragma unroll
            for (int rr = 0; rr < 4; rr++) {
                float v1 = acc[mf][nf][rr]   + b1.e[rr];
                float v2 = acc[mf+4][nf][rr] + b2.e[rr];
                float sg = 1.f / (1.f + expf(-v2));
                hv.e[rr] = (bf16_t)(v1 * sg + (float)uv.e[rr]);
            }
            *(uint2*)&h2T[base + o] = hv.u;
        }
    }
}

// ------- projB: res/skip = {rw,sw}@h2 (MFMA) + epilogue -> out fp32 -------
// m = l (128); n = o rows [n0, n0+128) of 512 {0..255 res, 256..511 skip}.
__global__ __launch_bounds__(256) void k_projB(const bf16_t* __restrict__ h2T,
                                               const bf16_t* __restrict__ rsb,
                                               const float* __restrict__ rb,
                                               const float* __restrict__ sb,
                                               const float* __restrict__ x,
                                               float* __restrict__ out) {
    int bid = blockIdx.x;
    int ng = bid >> 9;
    int b  = (bid >> 3) & 63;
    int l0 = (bid & 7) << 7;
    int n0 = ng << 7;
    __shared__ __align__(16) bf16_t at[128*32];
    __shared__ __align__(16) bf16_t bt[128*32];
    int tid = threadIdx.x, lane = tid & 63, wv = tid >> 6;
    int q = lane >> 4, ln = lane & 15;
    int r = tid >> 2, seg = tid & 3;

    f32x4 acc[8][2];
#pragma unroll
    for (int i = 0; i < 8; i++) { acc[i][0] = (f32x4){0.f,0.f,0.f,0.f};
                                  acc[i][1] = (f32x4){0.f,0.f,0.f,0.f}; }

    for (int k0 = 0; k0 < 256; k0 += 32) {
        __syncthreads();
        *(uint4*)&at[r*32 + seg*8] =
            *(const uint4*)&h2T[((size_t)b*Lq + l0 + r)*256 + k0 + seg*8];
        *(uint4*)&at[(r+64)*32 + seg*8] =
            *(const uint4*)&h2T[((size_t)b*Lq + l0 + 64 + r)*256 + k0 + seg*8];
        *(uint4*)&bt[r*32 + seg*8] =
            *(const uint4*)&rsb[(n0 + r)*256 + k0 + seg*8];
        *(uint4*)&bt[(r+64)*32 + seg*8] =
            *(const uint4*)&rsb[(n0 + 64 + r)*256 + k0 + seg*8];
        __syncthreads();
        bf16x8 bfr[2];
        bfr[0] = *(const bf16x8*)&bt[(wv*32 + ln)*32 + q*8];
        bfr[1] = *(const bf16x8*)&bt[(wv*32 + 16 + ln)*32 + q*8];
#pragma unroll
        for (int mf = 0; mf < 8; mf++) {
            bf16x8 af = *(const bf16x8*)&at[(mf*16 + ln)*32 + q*8];
            acc[mf][0] = __builtin_amdgcn_mfma_f32_16x16x32_bf16(af, bfr[0], acc[mf][0], 0,0,0);
            acc[mf][1] = __builtin_amdgcn_mfma_f32_16x16x32_bf16(af, bfr[1], acc[mf][1], 0,0,0);
        }
    }
#pragma unroll
    for (int nf = 0; nf < 2; nf++) {
        int o = n0 + wv*32 + nf*16 + ln;
#pragma unroll
        for (int mf = 0; mf < 8; mf++) {
            int l = l0 + mf*16 + q*4;
            if (ng < 2) {
                F4 xv; xv.v = *(const float4*)&x[((size_t)b*Hq + o)*Lq + l];
                float rbv = rb[o];
                F4 ov;
#pragma unroll
                for (int rr = 0; rr < 4; rr++)
                    ov.e[rr] = (acc[mf][nf][rr] + rbv + xv.e[rr]) * 0.70710678118654752f;
                *(float4*)&out[((size_t)b*Hq + o)*Lq + l] = ov.v;
            } else {
                int c = o - 256;
                float sbv = sb[c];
                F4 ov;
#pragma unroll
                for (int rr = 0; rr < 4; rr++)
                    ov.e[rr] = acc[mf][nf][rr] + sbv;
                *(float4*)&out[(size_t)BHL + ((size_t)b*HSq + c)*Lq + l] = ov.v;
            }
        }
    }
}

extern "C" void kernel_launch(void* const* d_in, const int* in_sizes, int n_in,
                              void* d_out, int out_size, void* d_ws, size_t ws_size,
                              hipStream_t stream) {
    const float* x      = (const float*)d_in[0];
    const float* emb    = (const float*)d_in[1];
    const float* gnw    = (const float*)d_in[2];
    const float* gnb    = (const float*)d_in[3];
    const float* dpw    = (const float*)d_in[4];
    const float* dpb    = (const float*)d_in[5];
    const float* log_dt = (const float*)d_in[6];
    const float* Are    = (const float*)d_in[7];
    const float* Aim    = (const float*)d_in[8];
    const float* Cre    = (const float*)d_in[9];
    const float* Cim    = (const float*)d_in[10];
    const float* Dp     = (const float*)d_in[11];
    const float* ow     = (const float*)d_in[12];
    const float* ob     = (const float*)d_in[13];
    const float* rw     = (const float*)d_in[14];
    const float* rb     = (const float*)d_in[15];
    const float* sw     = (const float*)d_in[16];
    const float* sb     = (const float*)d_in[17];
    float* out = (float*)d_out;

    bf16_t* ub   = (bf16_t*)d_ws;                    // [B][H][L] bf16
    bf16_t* ubT  = ub   + (size_t)BHL;               // [B][L][H] bf16
    bf16_t* gy   = ubT  + (size_t)BHL;               // [B][H][L] bf16
    bf16_t* Krev = gy   + (size_t)BHL;               // [H][1536] bf16
    bf16_t* owb  = Krev + (size_t)256*1536;          // [512][256] bf16
    bf16_t* rsb  = owb  + (size_t)512*256;           // [512][256] bf16
    float*  dprj = (float*)(rsb + (size_t)512*256);  // [B][H]
    float*  stats = dprj + (size_t)Bq*Hq;            // [B*G][2]
    bf16_t* gyT = ub;    // reuse: ub dead after k_conv
    bf16_t* h2T = gy;    // reuse: gy dead after second k_tr

    k_stats<<<Bq*Gq, 256, 0, stream>>>(x, stats);
    k_dproj<<<Bq*Hq/256, 256, 0, stream>>>(emb, dpw, dpb, dprj);
    k_u<<<2048, 256, 0, stream>>>(x, stats, gnw, gnb, dprj, ub);
    k_tr<<<Bq*64, 256, 0, stream>>>(ub, ubT);
    k_wcvt<<<512, 256, 0, stream>>>(ow, rw, sw, owb, rsb);
    k_kern<<<Hq, 256, 0, stream>>>(log_dt, Are, Aim, Cre, Cim, Krev);
    k_conv<<<Hq*4, 256, 0, stream>>>(ub, Krev, Dp, gy);
    k_tr<<<Bq*64, 256, 0, stream>>>(gy, gyT);
    k_projA<<<2048, 256, 0, stream>>>(gyT, owb, ob, ubT, h2T);
    k_projB<<<2048, 256, 0, stream>>>(h2T, rsb, rb, sb, x, out);
}